// Round 5
// baseline (595.998 us; speedup 1.0000x reference)
//
#include <hip/hip_runtime.h>
#include <cstdint>
#include <cstddef>

typedef __bf16 bf16x8 __attribute__((ext_vector_type(8)));
typedef __bf16 bf16x4 __attribute__((ext_vector_type(4)));
typedef short short4v __attribute__((ext_vector_type(4)));
typedef float f32x4 __attribute__((ext_vector_type(4)));

__device__ __forceinline__ uint16_t f2bf(float f) {
    union { float f; uint32_t u; } v; v.f = f;
    uint32_t r = (v.u + 0x7fffu + ((v.u >> 16) & 1u)) >> 16;
    return (uint16_t)r;
}
__device__ __forceinline__ float bf2f(uint16_t h) {
    union { uint32_t u; float f; } v; v.u = ((uint32_t)h) << 16;
    return v.f;
}

// K=16 bf16 MFMA (A/B: 4 bf16 per lane, k = quad*4+j).
// NOTE: __has_builtin test must live INSIDE the function body — on the HIP
// host pass no amdgcn builtin exists and a top-level #error kills the build.
__device__ __forceinline__ f32x4 mfma16(short4v a, short4v b, f32x4 c) {
#if __has_builtin(__builtin_amdgcn_mfma_f32_16x16x16bf16_1k)
    return __builtin_amdgcn_mfma_f32_16x16x16bf16_1k(a, b, c, 0, 0, 0);
#elif __has_builtin(__builtin_amdgcn_mfma_f32_16x16x16_bf16)
    union { short4v s; bf16x4 h; } ua, ub; ua.s = a; ub.s = b;
    return __builtin_amdgcn_mfma_f32_16x16x16_bf16(ua.h, ub.h, c, 0, 0, 0);
#else
    return c;   // host-pass stub, never executed
#endif
}

// async 16B/lane global->LDS (wave-uniform LDS base; HW scatters lane i at +16i)
__device__ __forceinline__ void gload_lds16(const void* g, void* l) {
    __builtin_amdgcn_global_load_lds(
        (__attribute__((address_space(1))) void*)g,
        (__attribute__((address_space(3))) void*)l, 16, 0, 0);
}

// ---------------------------------------------------------------------------
// hidden fp32 -> bf16
// ---------------------------------------------------------------------------
__global__ __launch_bounds__(256) void k_tobf16(const float* __restrict__ X,
                                                uint16_t* __restrict__ Y) {
    int i = (blockIdx.x * 256 + threadIdx.x) * 4;
    f32x4 v = *reinterpret_cast<const f32x4*>(X + i);
    uint2 o;
    o.x = (uint32_t)f2bf(v[0]) | ((uint32_t)f2bf(v[1]) << 16);
    o.y = (uint32_t)f2bf(v[2]) | ((uint32_t)f2bf(v[3]) << 16);
    *reinterpret_cast<uint2*>(Y + i) = o;
}

// ---------------------------------------------------------------------------
// Weight transpose + convert: W (R x C, fp32) -> Wt (C x R, bf16)
// ---------------------------------------------------------------------------
__global__ __launch_bounds__(256) void k_transpose_w(const float* __restrict__ W,
                                                     uint16_t* __restrict__ Wt,
                                                     int R, int C) {
    __shared__ uint16_t tile[32][33];
    int c0 = blockIdx.x * 32;
    int r0 = blockIdx.y * 32;
    int t = threadIdx.x;
    int tc = t & 31, tr = t >> 5;
#pragma unroll
    for (int i = 0; i < 4; ++i) {
        int r = tr * 4 + i;
        tile[r][tc] = f2bf(W[(size_t)(r0 + r) * C + c0 + tc]);
    }
    __syncthreads();
#pragma unroll
    for (int i = 0; i < 4; ++i) {
        int c = tr * 4 + i;
        Wt[(size_t)(c0 + c) * R + r0 + tc] = tile[tc][c];
    }
}

// ---------------------------------------------------------------------------
// V transpose: V (2048 x 512 bf16) -> Vt (4 x 128 x 2048 bf16)
// ---------------------------------------------------------------------------
__global__ __launch_bounds__(256) void k_transpose_v(const uint16_t* __restrict__ V,
                                                     uint16_t* __restrict__ Vt) {
    __shared__ uint16_t tile[32][33];
    int c0 = blockIdx.x * 32;
    int s0 = blockIdx.y * 32;
    int t = threadIdx.x;
    int tc = t & 31, tr = t >> 5;
#pragma unroll
    for (int i = 0; i < 4; ++i) {
        int s = tr * 4 + i;
        tile[s][tc] = V[(size_t)(s0 + s) * 512 + c0 + tc];
    }
    __syncthreads();
#pragma unroll
    for (int i = 0; i < 4; ++i) {
        int c = c0 + tr * 4 + i;
        Vt[(size_t)c * 2048 + s0 + tc] = tile[tc][tr * 4 + i];
    }
}

// ---------------------------------------------------------------------------
// RoPE in place + row norms. Q scaled by (1/sqrt(128))*log2(e).
// Qn[h][s] = ||stored q row||, Kn[kvh][s] = ||k row|| (rotation-invariant).
// ---------------------------------------------------------------------------
__global__ __launch_bounds__(256) void k_rope(uint16_t* __restrict__ Q,
                                              uint16_t* __restrict__ K,
                                              const int* __restrict__ pos_ids,
                                              float* __restrict__ Qn,
                                              float* __restrict__ Kn) {
    int idx = blockIdx.x * 256 + threadIdx.x;
    int d = idx & 63;
    int s = idx >> 6;
    int lane = threadIdx.x & 63;
    float pos = (float)pos_ids[s];
    float ang = pos * exp2f((float)d * (-19.931568569324174f / 64.0f));
    float cs = cosf(ang), sn = sinf(ang);
    const float qscale = 0.08838834764831845f * 1.4426950408889634f;
    uint16_t* q = Q + (size_t)s * 3584 + d;
#pragma unroll
    for (int h = 0; h < 28; ++h) {
        float x1 = bf2f(q[h * 128]);
        float x2 = bf2f(q[h * 128 + 64]);
        q[h * 128]      = f2bf((x1 * cs - x2 * sn) * qscale);
        q[h * 128 + 64] = f2bf((x2 * cs + x1 * sn) * qscale);
        float ss = x1 * x1 + x2 * x2;
#pragma unroll
        for (int off = 32; off >= 1; off >>= 1)
            ss += __shfl_xor(ss, off, 64);
        if (lane == 0) Qn[h * 2048 + s] = qscale * sqrtf(ss);
    }
    uint16_t* k = K + (size_t)s * 512 + d;
#pragma unroll
    for (int h = 0; h < 4; ++h) {
        float x1 = bf2f(k[h * 128]);
        float x2 = bf2f(k[h * 128 + 64]);
        k[h * 128]      = f2bf(x1 * cs - x2 * sn);
        k[h * 128 + 64] = f2bf(x2 * cs + x1 * sn);
        float ss = x1 * x1 + x2 * x2;
#pragma unroll
        for (int off = 32; off >= 1; off >>= 1)
            ss += __shfl_xor(ss, off, 64);
        if (lane == 0) Kn[h * 2048 + s] = sqrtf(ss);
    }
}

// Km[kvh] = max_s Kn[kvh][s]
__global__ __launch_bounds__(256) void k_kmax(const float* __restrict__ Kn,
                                              float* __restrict__ Km) {
    __shared__ float red[256];
    int tid = threadIdx.x;
    for (int kvh = 0; kvh < 4; ++kvh) {
        float mx = 0.f;
        for (int s = tid; s < 2048; s += 256)
            mx = fmaxf(mx, Kn[kvh * 2048 + s]);
        red[tid] = mx;
        __syncthreads();
        for (int off = 128; off >= 1; off >>= 1) {
            if (tid < off) red[tid] = fmaxf(red[tid], red[tid + off]);
            __syncthreads();
        }
        if (tid == 0) Km[kvh] = red[0];
        __syncthreads();
    }
}

// ---------------------------------------------------------------------------
// GEMM 64x128 tile, BK=32, global_load_lds width-16 staging.
// ---------------------------------------------------------------------------
#define BK 32

__global__ __launch_bounds__(256, 4) void k_gemm_qkv(
    const uint16_t* __restrict__ A,
    const uint16_t* __restrict__ WqT,
    const uint16_t* __restrict__ WkT,
    const uint16_t* __restrict__ WvT,
    uint16_t* __restrict__ Q,
    uint16_t* __restrict__ K,
    uint16_t* __restrict__ V)
{
    __shared__ uint16_t Als[64 * BK];
    __shared__ uint16_t Bls[128 * BK];

    int nt = blockIdx.x;
    int m0 = blockIdx.y * 64;

    const uint16_t* Bt; uint16_t* dst; int dstStride; int colBase;
    if (nt < 28)      { Bt = WqT + (size_t)nt * 128 * 3584;        dst = Q; dstStride = 3584; colBase = nt * 128; }
    else if (nt < 32) { Bt = WkT + (size_t)(nt - 28) * 128 * 3584; dst = K; dstStride = 512;  colBase = (nt - 28) * 128; }
    else              { Bt = WvT + (size_t)(nt - 32) * 128 * 3584; dst = V; dstStride = 512;  colBase = (nt - 32) * 128; }

    int tid = threadIdx.x;
    int w = tid >> 6, lane = tid & 63, quad = lane >> 4, l15 = lane & 15;
    int wm = (w >> 1) * 32, wn = (w & 1) * 64;

    int lrow = lane >> 2;
    int lcol = (lane & 3) * 8;

    const uint16_t* aS = A  + (size_t)(m0 + w * 16 + lrow) * 3584 + lcol;
    const uint16_t* bS = Bt + (size_t)(w * 32 + lrow) * 3584 + lcol;
    uint16_t* aD  = &Als[(w * 16) * BK];
    uint16_t* bD0 = &Bls[(w * 32) * BK];
    uint16_t* bD1 = &Bls[(w * 32 + 16) * BK];

    f32x4 acc[2][4] = {};

    for (int k0 = 0; k0 < 3584; k0 += BK) {
        __syncthreads();
        gload_lds16(aS + k0, aD);
        gload_lds16(bS + k0, bD0);
        gload_lds16(bS + k0 + (size_t)16 * 3584, bD1);
        __syncthreads();

        bf16x8 af[2], bfr[4];
#pragma unroll
        for (int i = 0; i < 2; ++i)
            af[i] = *reinterpret_cast<const bf16x8*>(&Als[(wm + i * 16 + l15) * BK + quad * 8]);
#pragma unroll
        for (int j = 0; j < 4; ++j)
            bfr[j] = *reinterpret_cast<const bf16x8*>(&Bls[(wn + j * 16 + l15) * BK + quad * 8]);
#pragma unroll
        for (int i = 0; i < 2; ++i)
#pragma unroll
            for (int j = 0; j < 4; ++j)
                acc[i][j] = __builtin_amdgcn_mfma_f32_16x16x32_bf16(af[i], bfr[j], acc[i][j], 0, 0, 0);
    }

#pragma unroll
    for (int i = 0; i < 2; ++i)
#pragma unroll
        for (int r = 0; r < 4; ++r) {
            int grow = m0 + wm + i * 16 + quad * 4 + r;
#pragma unroll
            for (int j = 0; j < 4; ++j) {
                int gcol = colBase + wn + j * 16 + l15;
                dst[(size_t)grow * dstStride + gcol] = f2bf(acc[i][j][r]);
            }
        }
}

__global__ __launch_bounds__(256, 4) void k_gemm_o(
    const uint16_t* __restrict__ A,
    const uint16_t* __restrict__ WoT,
    float* __restrict__ out)
{
    __shared__ uint16_t Als[64 * BK];
    __shared__ uint16_t Bls[128 * BK];

    int nt = blockIdx.x;
    int m0 = blockIdx.y * 64;
    const uint16_t* Bt = WoT + (size_t)nt * 128 * 3584;

    int tid = threadIdx.x;
    int w = tid >> 6, lane = tid & 63, quad = lane >> 4, l15 = lane & 15;
    int wm = (w >> 1) * 32, wn = (w & 1) * 64;

    int lrow = lane >> 2;
    int lcol = (lane & 3) * 8;

    const uint16_t* aS = A  + (size_t)(m0 + w * 16 + lrow) * 3584 + lcol;
    const uint16_t* bS = Bt + (size_t)(w * 32 + lrow) * 3584 + lcol;
    uint16_t* aD  = &Als[(w * 16) * BK];
    uint16_t* bD0 = &Bls[(w * 32) * BK];
    uint16_t* bD1 = &Bls[(w * 32 + 16) * BK];

    f32x4 acc[2][4] = {};

    for (int k0 = 0; k0 < 3584; k0 += BK) {
        __syncthreads();
        gload_lds16(aS + k0, aD);
        gload_lds16(bS + k0, bD0);
        gload_lds16(bS + k0 + (size_t)16 * 3584, bD1);
        __syncthreads();

        bf16x8 af[2], bfr[4];
#pragma unroll
        for (int i = 0; i < 2; ++i)
            af[i] = *reinterpret_cast<const bf16x8*>(&Als[(wm + i * 16 + l15) * BK + quad * 8]);
#pragma unroll
        for (int j = 0; j < 4; ++j)
            bfr[j] = *reinterpret_cast<const bf16x8*>(&Bls[(wn + j * 16 + l15) * BK + quad * 8]);
#pragma unroll
        for (int i = 0; i < 2; ++i)
#pragma unroll
            for (int j = 0; j < 4; ++j)
                acc[i][j] = __builtin_amdgcn_mfma_f32_16x16x32_bf16(af[i], bfr[j], acc[i][j], 0, 0, 0);
    }

#pragma unroll
    for (int i = 0; i < 2; ++i)
#pragma unroll
        for (int r = 0; r < 4; ++r) {
            int grow = m0 + wm + i * 16 + quad * 4 + r;
#pragma unroll
            for (int j = 0; j < 4; ++j) {
                int gcol = nt * 128 + wn + j * 16 + l15;
                out[(size_t)grow * 3584 + gcol] = acc[i][j][r];
            }
        }
}

// ---------------------------------------------------------------------------
// Flash attention: split-K across 4 waves, fixed-m softmax (m = ||q||*max||k||,
// Cauchy-Schwarz bound => p<=1, shift-invariance => exact softmax), transposed
// QK^T so score C-tiles feed PV's K=16 A-operand directly from registers.
// Zero LDS / zero cross-lane in the main loop.
// ---------------------------------------------------------------------------
__global__ __launch_bounds__(256, 2) void k_flash(
    const uint16_t* __restrict__ Q,    // 2048x3584 (roped, *1/sqrt(d)*log2e)
    const uint16_t* __restrict__ K,    // 2048x512  (roped)
    const uint16_t* __restrict__ Vt,   // 4x128x2048
    const float* __restrict__ Qn,      // 28x2048 row norms of stored Q
    const float* __restrict__ Km,      // 4 max ||k||
    uint16_t* __restrict__ O)          // 2048x3584
{
    __shared__ uint16_t AccS[4][32 * 128];
    __shared__ float Ll[4][32];

    int h  = blockIdx.x;               // 0..27
    int qb = 63 - (int)blockIdx.y;     // heavy first
    int kvh = h / 7;
    int tid = threadIdx.x;
    int w = tid >> 6, lane = tid & 63, quad = lane >> 4, l15 = lane & 15;
    int q0 = qb * 32;

    const uint16_t* Kh = K + kvh * 128;
    const uint16_t* Vh = Vt + (size_t)kvh * 128 * 2048;

    // Q fragments (B-operand of transposed QK: B[k=d=quad*8+j][n=q=l15])
    bf16x8 qf[2][4];
#pragma unroll
    for (int s = 0; s < 2; ++s) {
        const uint16_t* qp = Q + (size_t)(q0 + s * 16 + l15) * 3584 + h * 128 + quad * 8;
#pragma unroll
        for (int c = 0; c < 4; ++c)
            qf[s][c] = *reinterpret_cast<const bf16x8*>(qp + c * 32);
    }

    float km = Km[kvh];
    float mrow[2];
    mrow[0] = Qn[h * 2048 + q0 + l15] * km;
    mrow[1] = Qn[h * 2048 + q0 + 16 + l15] * km;

    f32x4 acc[2][8] = {};
    float l_lane[2] = {0.f, 0.f};

    int tmax = qb;
    bf16x8 kf[8];                      // A-operand: A[m=key=l15][k=d=quad*8+j]
    int t = w;
    if (t <= tmax) {
        const uint16_t* kp = Kh + (size_t)(t * 32 + l15) * 512 + quad * 8;
#pragma unroll
        for (int nt = 0; nt < 2; ++nt)
#pragma unroll
            for (int c = 0; c < 4; ++c)
                kf[nt * 4 + c] = *reinterpret_cast<const bf16x8*>(kp + (size_t)nt * 16 * 512 + c * 32);
    }

    for (; t <= tmax; t += 4) {
        int kb = t * 32;

        // V B-operands (K=16): B[k=key=quad*4+j][n=d=dt*16+l15]
        short4v vf[2][8];
#pragma unroll
        for (int sub = 0; sub < 2; ++sub)
#pragma unroll
            for (int dt = 0; dt < 8; ++dt)
                vf[sub][dt] = *reinterpret_cast<const short4v*>(
                    Vh + (size_t)(dt * 16 + l15) * 2048 + kb + sub * 16 + quad * 4);

        // transposed QK^T: sc[s][nt] = S^T tile, row=key=quad*4+r, col=q=l15
        f32x4 sc[2][2] = {};
#pragma unroll
        for (int nt = 0; nt < 2; ++nt)
#pragma unroll
            for (int c = 0; c < 4; ++c) {
                sc[0][nt] = __builtin_amdgcn_mfma_f32_16x16x32_bf16(kf[nt * 4 + c], qf[0][c], sc[0][nt], 0, 0, 0);
                sc[1][nt] = __builtin_amdgcn_mfma_f32_16x16x32_bf16(kf[nt * 4 + c], qf[1][c], sc[1][nt], 0, 0, 0);
            }

        // prefetch next owned K tile (regs free after QK)
        int tn = t + 4;
        if (tn <= tmax) {
            const uint16_t* kp = Kh + (size_t)(tn * 32 + l15) * 512 + quad * 8;
#pragma unroll
            for (int nt = 0; nt < 2; ++nt)
#pragma unroll
                for (int c = 0; c < 4; ++c)
                    kf[nt * 4 + c] = *reinterpret_cast<const bf16x8*>(kp + (size_t)nt * 16 * 512 + c * 32);
        }

        // causal mask (last tile only)
        if (kb + 31 > q0) {
#pragma unroll
            for (int s = 0; s < 2; ++s)
#pragma unroll
                for (int nt = 0; nt < 2; ++nt) {
                    int qq = q0 + s * 16 + l15;
#pragma unroll
                    for (int r = 0; r < 4; ++r) {
                        int key = kb + nt * 16 + quad * 4 + r;
                        if (key > qq) sc[s][nt][r] = -1e30f;
                    }
                }
        }

        // fixed-m softmax: p = exp2(sc - m_q); accumulate l per-lane
        short4v pf[2][2];
#pragma unroll
        for (int s = 0; s < 2; ++s)
#pragma unroll
            for (int nt = 0; nt < 2; ++nt) {
                float p0 = __builtin_amdgcn_exp2f(sc[s][nt][0] - mrow[s]);
                float p1 = __builtin_amdgcn_exp2f(sc[s][nt][1] - mrow[s]);
                float p2 = __builtin_amdgcn_exp2f(sc[s][nt][2] - mrow[s]);
                float p3 = __builtin_amdgcn_exp2f(sc[s][nt][3] - mrow[s]);
                l_lane[s] += (p0 + p1) + (p2 + p3);
                short4v pk;
                pk[0] = (short)f2bf(p0); pk[1] = (short)f2bf(p1);
                pk[2] = (short)f2bf(p2); pk[3] = (short)f2bf(p3);
                pf[s][nt] = pk;
            }

        // PV: acc[q][d] += P(16 keys) x V, K=16 MFMAs, operands all in regs
#pragma unroll
        for (int sub = 0; sub < 2; ++sub)
#pragma unroll
            for (int dt = 0; dt < 8; ++dt) {
                acc[0][dt] = mfma16(pf[0][sub], vf[sub][dt], acc[0][dt]);
                acc[1][dt] = mfma16(pf[1][sub], vf[sub][dt], acc[1][dt]);
            }
    }

    // finalize l: sum the 4 quads' partials (keys are distributed over quads)
#pragma unroll
    for (int s = 0; s < 2; ++s) {
        float l = l_lane[s];
        l += __shfl_xor(l, 16, 64);
        l += __shfl_xor(l, 32, 64);
        l_lane[s] = l;
    }

    // write per-wave partials (directly summable: same m across waves)
    uint16_t* As = &AccS[w][0];
#pragma unroll
    for (int s = 0; s < 2; ++s)
#pragma unroll
        for (int dt = 0; dt < 8; ++dt)
#pragma unroll
            for (int r = 0; r < 4; ++r)
                As[(s * 16 + quad * 4 + r) * 128 + dt * 16 + l15] = f2bf(acc[s][dt][r]);
    if (quad == 0) {
        Ll[w][l15]      = l_lane[0];
        Ll[w][16 + l15] = l_lane[1];
    }
    __syncthreads();

    // combine 4 partials; wave w -> rows w*8..w*8+7, lane -> (row, 16-col chunk)
    {
        int rowl = w * 8 + (lane >> 3);
        int c16 = (lane & 7) * 16;
        float lt = Ll[0][rowl] + Ll[1][rowl] + Ll[2][rowl] + Ll[3][rowl];
        float inv = __builtin_amdgcn_rcpf(lt);

        float o[16];
#pragma unroll
        for (int j = 0; j < 16; ++j) o[j] = 0.f;
#pragma unroll
        for (int sl = 0; sl < 4; ++sl) {
            const uint16_t* src = &AccS[sl][rowl * 128 + c16];
#pragma unroll
            for (int j = 0; j < 16; ++j)
                o[j] += bf2f(src[j]);
        }
        uint16_t ob[16];
#pragma unroll
        for (int j = 0; j < 16; ++j) ob[j] = f2bf(o[j] * inv);
        uint16_t* op = O + (size_t)(q0 + rowl) * 3584 + h * 128 + c16;
        *reinterpret_cast<uint4*>(op)     = *reinterpret_cast<uint4*>(&ob[0]);
        *reinterpret_cast<uint4*>(op + 8) = *reinterpret_cast<uint4*>(&ob[8]);
    }
}

// ---------------------------------------------------------------------------
extern "C" void kernel_launch(void* const* d_in, const int* in_sizes, int n_in,
                              void* d_out, int out_size, void* d_ws, size_t ws_size,
                              hipStream_t stream) {
    const float* hidden = (const float*)d_in[0];
    const int*   pos    = (const int*)d_in[1];
    const float* Wq     = (const float*)d_in[2];
    const float* Wk     = (const float*)d_in[3];
    const float* Wv     = (const float*)d_in[4];
    const float* Wo     = (const float*)d_in[5];
    float* out = (float*)d_out;

    char* ws = (char*)d_ws;
    size_t o = 0;
    uint16_t* WqT = (uint16_t*)(ws + o); o += (size_t)3584 * 3584 * 2;
    uint16_t* WkT = (uint16_t*)(ws + o); o += (size_t)512  * 3584 * 2;
    uint16_t* WvT = (uint16_t*)(ws + o); o += (size_t)512  * 3584 * 2;
    uint16_t* WoT = (uint16_t*)(ws + o); o += (size_t)3584 * 3584 * 2;
    uint16_t* Xb  = (uint16_t*)(ws + o); o += (size_t)2048 * 3584 * 2;  // aliased as At
    uint16_t* Qb  = (uint16_t*)(ws + o); o += (size_t)2048 * 3584 * 2;
    uint16_t* Kb  = (uint16_t*)(ws + o); o += (size_t)2048 * 512  * 2;
    uint16_t* Vb  = (uint16_t*)(ws + o); o += (size_t)2048 * 512  * 2;
    uint16_t* Vt  = (uint16_t*)(ws + o); o += (size_t)2048 * 512  * 2;
    float*    Qn  = (float*)(ws + o);    o += (size_t)28 * 2048 * 4;
    float*    Kn  = (float*)(ws + o);    o += (size_t)4  * 2048 * 4;
    float*    Km  = (float*)(ws + o);    o += 4 * 4;
    uint16_t* At  = Xb;

    k_tobf16<<<dim3(7168), 256, 0, stream>>>(hidden, Xb);
    k_transpose_w<<<dim3(112, 112), 256, 0, stream>>>(Wq, WqT, 3584, 3584);
    k_transpose_w<<<dim3(16, 112),  256, 0, stream>>>(Wk, WkT, 3584, 512);
    k_transpose_w<<<dim3(16, 112),  256, 0, stream>>>(Wv, WvT, 3584, 512);
    k_transpose_w<<<dim3(112, 112), 256, 0, stream>>>(Wo, WoT, 3584, 3584);

    k_gemm_qkv<<<dim3(36, 32), 256, 0, stream>>>(Xb, WqT, WkT, WvT, Qb, Kb, Vb);
    k_rope<<<dim3(512), 256, 0, stream>>>(Qb, Kb, pos, Qn, Kn);
    k_kmax<<<dim3(1), 256, 0, stream>>>(Kn, Km);
    k_transpose_v<<<dim3(16, 64), 256, 0, stream>>>(Vb, Vt);
    k_flash<<<dim3(28, 64), 256, 0, stream>>>(Qb, Kb, Vt, Qn, Km, At);
    k_gemm_o<<<dim3(28, 32), 256, 0, stream>>>(At, WoT, out);
}